// Round 9
// baseline (437.414 us; speedup 1.0000x reference)
//
#include <hip/hip_runtime.h>

#define NB 512
#define SLOTS 32
#define D 1024
#define D4 256           // float4 per row
#define TC 8             // tokens per chunk
#define CAP 64
#define TAU_INV 10.0f
#define BT 512           // 8 waves

// ---- kernel 0: zero per-bucket counters ----
__global__ void k_zero(int* __restrict__ cnt) {
    if (threadIdx.x < NB) cnt[threadIdx.x] = 0;
}

// ---- kernel 1: per-bucket token lists (order nondeterministic; per-token
//      math is list-order-invariant → deterministic output) ----
__global__ void k_build(const int* __restrict__ tids, int n,
                        int* __restrict__ cnt, int* __restrict__ list) {
    int i = blockIdx.x * 256 + threadIdx.x;
    if (i < n) {
        int b = tids[i] & (NB - 1);
        int p = atomicAdd(&cnt[b], 1);
        if (p < CAP) list[b * CAP + p] = i;
    }
}

// ---- kernel 2: block = (bucket, parity). Part p owns tokens p,p+2,... of
//      its bucket (even/odd split balances stragglers). 8 waves, TC=8.
//      VGPR discipline: every phase's live set ≤ ~100 regs (R7/R8 spills).
__global__ __launch_bounds__(BT, 2)
void k_main(const float* __restrict__ query,    // [NT][D]
            const int*   __restrict__ tids,     // [NT]
            const float* __restrict__ skeys,    // [NB*SLOTS][D]
            const float* __restrict__ svals,    // [NB*SLOTS][D]
            const int*   __restrict__ stids,    // [NB*SLOTS]
            const float* __restrict__ centroid, // [NB][D]
            float*       __restrict__ out,      // [NT][D]
            const int*   __restrict__ cnt,
            const int*   __restrict__ list)
{
    const int bucket = blockIdx.x & (NB - 1);   // parts share XCD (512%8==0)
    const int part   = blockIdx.x >> 9;         // 0/1
    const int tidx   = threadIdx.x;             // 0..511
    const int lane   = tidx & 63;
    const int wid    = tidx >> 6;               // 0..7

    const int count = min(cnt[bucket], CAP);
    const int ncnt  = (count - part + 1) >> 1;  // tokens owned by this part
    if (ncnt <= 0) return;

    __shared__ float s_uq[TC][D];               // 32 KB
    __shared__ float s_scores[TC][SLOTS];
    __shared__ float s_probs[TC][SLOTS];
    __shared__ int   s_tok[TC];
    __shared__ int   s_ttid[TC];

    const int slot_tid = stids[bucket * SLOTS + (lane & 31)];
    const float4* kb = (const float4*)(skeys + (size_t)bucket * SLOTS * D);
    const float4* vb = (const float4*)(svals + (size_t)bucket * SLOTS * D);
    const float4* cb = (const float4*)(centroid + (size_t)bucket * D);

    for (int c0 = 0; c0 < ncnt; c0 += TC) {
        const int nt = min(TC, ncnt - c0);

        // ---- query phase: wave w owns token w (~55 live regs) ----
        if (wid < nt) {
            const int tok = list[bucket * CAP + part + 2 * (c0 + wid)];
            const float4* q4 = (const float4*)(query + (size_t)tok * D);
            float4 qv[4], anc[4];
            float ss = 0.f;
            #pragma unroll
            for (int j = 0; j < 4; ++j) {
                qv[j]  = q4[lane + 64 * j];
                anc[j] = cb[lane + 64 * j];
                ss += qv[j].x*qv[j].x + qv[j].y*qv[j].y + qv[j].z*qv[j].z + qv[j].w*qv[j].w;
            }
            #pragma unroll
            for (int off = 32; off >= 1; off >>= 1) ss += __shfl_xor(ss, off);
            const float qn = 0.5f / fmaxf(sqrtf(ss), 1e-12f);   // folds ALPHA
            float4 uv[4];
            float ss2 = 0.f;
            #pragma unroll
            for (int j = 0; j < 4; ++j) {
                uv[j].x = qv[j].x * qn + 0.5f * anc[j].x;
                uv[j].y = qv[j].y * qn + 0.5f * anc[j].y;
                uv[j].z = qv[j].z * qn + 0.5f * anc[j].z;
                uv[j].w = qv[j].w * qn + 0.5f * anc[j].w;
                ss2 += uv[j].x*uv[j].x + uv[j].y*uv[j].y + uv[j].z*uv[j].z + uv[j].w*uv[j].w;
            }
            #pragma unroll
            for (int off = 32; off >= 1; off >>= 1) ss2 += __shfl_xor(ss2, off);
            const float un = 1.0f / fmaxf(sqrtf(ss2), 1e-12f);
            #pragma unroll
            for (int j = 0; j < 4; ++j) {
                ((float4*)s_uq[wid])[lane + 64 * j] =
                    make_float4(uv[j].x*un, uv[j].y*un, uv[j].z*un, uv[j].w*un);
            }
            if (lane == 0) { s_tok[wid] = tok; s_ttid[wid] = tids[tok]; }
        }
        __syncthreads();   // barrier 1: s_uq visible to all

        // ---- score phase: 2 rounds; wave owns 2 slots/round (~70 live) ----
        #pragma unroll
        for (int rnd = 0; rnd < 2; ++rnd) {
            const int sbase = rnd * 16 + wid * 2;
            const float4* k0 = kb + (size_t)sbase * D4;
            const float4* k1 = k0 + D4;
            float4 ka[4], kc[4];
            #pragma unroll
            for (int j = 0; j < 4; ++j) {
                ka[j] = k0[lane + 64 * j];
                kc[j] = k1[lane + 64 * j];
            }
            float P[16];
            #pragma unroll
            for (int i = 0; i < 16; ++i) P[i] = 0.f;
            #pragma unroll
            for (int j = 0; j < 4; ++j) {
                #pragma unroll
                for (int t = 0; t < TC; ++t) {
                    const float4 u = ((const float4*)s_uq[t])[lane + 64 * j];
                    P[t*2+0] += u.x*ka[j].x + u.y*ka[j].y + u.z*ka[j].z + u.w*ka[j].w;
                    P[t*2+1] += u.x*kc[j].x + u.y*kc[j].y + u.z*kc[j].z + u.w*kc[j].w;
                }
            }
            // batched halving-reduce: 16 values, 17 shfl total (R8-verified).
            #pragma unroll
            for (int k = 0; k < 4; ++k) {
                const int o = 1 << k;
                const int half = 8 >> k;
                const bool hi = (lane & o) != 0;
                #pragma unroll
                for (int i = 0; i < half; ++i) {
                    const float send = hi ? P[i] : P[i + half];
                    const float keep = hi ? P[i + half] : P[i];
                    P[i] = keep + __shfl_xor(send, o);
                }
            }
            P[0] += __shfl_xor(P[0], 16);
            P[0] += __shfl_xor(P[0], 32);
            if (lane < 16) {
                const int id = ((lane & 1) << 3) | ((lane & 2) << 1)
                             | ((lane & 4) >> 1) | ((lane & 8) >> 3);  // bitrev4
                s_scores[id >> 1][sbase + (id & 1)] = P[0];
            }
        }
        __syncthreads();   // barrier 2: s_scores visible

        // ---- softmax + hard-match: wave w owns token w (wave-private out) ----
        if (wid < nt && lane < 32) {
            const float sc = s_scores[wid][lane];
            float m = sc;
            #pragma unroll
            for (int off = 16; off >= 1; off >>= 1) m = fmaxf(m, __shfl_xor(m, off));
            const float e = __expf((sc - m) * TAU_INV);
            const float f = (slot_tid == s_ttid[wid]) ? 1.f : 0.f;
            float es = e, ms = f;
            #pragma unroll
            for (int off = 16; off >= 1; off >>= 1) {
                es += __shfl_xor(es, off);
                ms += __shfl_xor(ms, off);
            }
            s_probs[wid][lane] = (ms > 0.f) ? f / (ms + 1e-9f) : e / es;
        }
        // no barrier: value phase of wave w reads only s_probs[w] (same wave)

        // ---- value phase: wave w owns token w; 4-row rotation (~95 live) ----
        if (wid < nt) {
            float4 acc[4];
            #pragma unroll
            for (int j = 0; j < 4; ++j) acc[j] = make_float4(0.f, 0.f, 0.f, 0.f);
            float4 r0[4], r1[4], r2[4], r3[4];
            #pragma unroll
            for (int j = 0; j < 4; ++j) {
                r0[j] = vb[0 * D4 + lane + 64 * j];
                r1[j] = vb[1 * D4 + lane + 64 * j];
                r2[j] = vb[2 * D4 + lane + 64 * j];
                r3[j] = vb[3 * D4 + lane + 64 * j];
            }
            #pragma unroll
            for (int s = 0; s < SLOTS; s += 4) {
                const float w0 = s_probs[wid][s + 0];   // LDS broadcast
                const float w1 = s_probs[wid][s + 1];
                const float w2 = s_probs[wid][s + 2];
                const float w3 = s_probs[wid][s + 3];
                #pragma unroll
                for (int j = 0; j < 4; ++j) {
                    acc[j].x += w0*r0[j].x + w1*r1[j].x + w2*r2[j].x + w3*r3[j].x;
                    acc[j].y += w0*r0[j].y + w1*r1[j].y + w2*r2[j].y + w3*r3[j].y;
                    acc[j].z += w0*r0[j].z + w1*r1[j].z + w2*r2[j].z + w3*r3[j].z;
                    acc[j].w += w0*r0[j].w + w1*r1[j].w + w2*r2[j].w + w3*r3[j].w;
                }
                if (s + 4 < SLOTS) {
                    #pragma unroll
                    for (int j = 0; j < 4; ++j) {
                        r0[j] = vb[(s + 4) * D4 + lane + 64 * j];
                        r1[j] = vb[(s + 5) * D4 + lane + 64 * j];
                        r2[j] = vb[(s + 6) * D4 + lane + 64 * j];
                        r3[j] = vb[(s + 7) * D4 + lane + 64 * j];
                    }
                }
            }
            float4* o4 = (float4*)(out + (size_t)s_tok[wid] * D);
            #pragma unroll
            for (int j = 0; j < 4; ++j) o4[lane + 64 * j] = acc[j];
        }
        // no trailing barrier: next query phase writes only wave-owned rows;
        // cross-wave readers (score phase) are fenced by barrier 1.
    }
}

extern "C" void kernel_launch(void* const* d_in, const int* in_sizes, int n_in,
                              void* d_out, int out_size, void* d_ws, size_t ws_size,
                              hipStream_t stream) {
    const float* query    = (const float*)d_in[0];
    const int*   tids     = (const int*)  d_in[1];
    const float* skeys    = (const float*)d_in[2];
    const float* svals    = (const float*)d_in[3];
    const int*   stids    = (const int*)  d_in[4];
    const float* centroid = (const float*)d_in[5];
    float* out = (float*)d_out;
    const int n_tokens = in_sizes[1];

    int* cnt  = (int*)d_ws;             // [NB]
    int* list = cnt + NB;               // [NB*CAP]

    k_zero<<<1, NB, 0, stream>>>(cnt);
    k_build<<<(n_tokens + 255) / 256, 256, 0, stream>>>(tids, n_tokens, cnt, list);
    k_main<<<NB * 2, BT, 0, stream>>>(query, tids, skeys, svals, stids,
                                      centroid, out, cnt, list);
}

// Round 10
// 62.192 us; speedup vs baseline: 7.0332x; 7.0332x over previous
//
#include <hip/hip_runtime.h>

#define NB 512
#define SLOTS 32
#define D 1024
#define D4 256           // D/4 (float4 per row)
#define TC 16            // tokens per chunk
#define CAP 64           // list capacity per bucket
#define TAU_INV 10.0f
#define BT 512           // threads per block (8 waves)

// ---- kernel 0: zero the per-bucket counters ----
__global__ void k_zero(int* __restrict__ cnt) {
    if (threadIdx.x < NB) cnt[threadIdx.x] = 0;
}

// ---- kernel 1: build per-bucket token lists (order nondeterministic, but
//      per-token math is order-invariant → deterministic output) ----
__global__ void k_build(const int* __restrict__ tids, int n,
                        int* __restrict__ cnt, int* __restrict__ list) {
    int i = blockIdx.x * 256 + threadIdx.x;
    if (i < n) {
        int b = tids[i] & (NB - 1);
        int p = atomicAdd(&cnt[b], 1);
        if (p < CAP) list[b * CAP + p] = i;
    }
}

// ---- kernel 2: one block per bucket, 8 waves. R5 structure (68us, 124 VGPR,
//      no spill) with ONE change: score reduce = batched paired-halving
//      (7 shfl / token vs 24) to cut the DS-pipe serialization.
__global__ __launch_bounds__(BT, 2)
void k_main(const float* __restrict__ query,    // [NT][D]
            const int*   __restrict__ tids,     // [NT]
            const float* __restrict__ skeys,    // [NB*SLOTS][D]
            const float* __restrict__ svals,    // [NB*SLOTS][D]
            const int*   __restrict__ stids,    // [NB*SLOTS]
            const float* __restrict__ centroid, // [NB][D]
            float*       __restrict__ out,      // [NT][D]
            const int*   __restrict__ cnt,
            const int*   __restrict__ list)
{
    const int bucket = blockIdx.x;
    const int tidx   = threadIdx.x;      // 0..511
    const int lane   = tidx & 63;
    const int wid    = tidx >> 6;        // 0..7

    const int count = min(cnt[bucket], CAP);
    if (count == 0) return;

    __shared__ float s_anchor[D];
    __shared__ float s_uq[TC][D];        // reused as partial-sum buffer in value phase
    __shared__ float s_scores[TC][SLOTS];
    __shared__ float s_probs[TC][SLOTS];
    __shared__ int   s_tok[TC];
    __shared__ int   s_ttid[TC];

    if (tidx < D4)
        ((float4*)s_anchor)[tidx] = ((const float4*)centroid)[bucket * D4 + tidx];
    __syncthreads();

    for (int c0 = 0; c0 < count; c0 += TC) {
        const int nt = min(TC, count - c0);

        // ---- unified queries: wave w owns tokens w, w+8 ----
        for (int t = wid; t < nt; t += 8) {
            const int tok = list[bucket * CAP + c0 + t];
            const float4* q4 = (const float4*)(query + (size_t)tok * D);
            float4 qv[4];
            float ss = 0.f;
            #pragma unroll
            for (int j = 0; j < 4; ++j) {
                qv[j] = q4[lane + 64 * j];
                ss += qv[j].x*qv[j].x + qv[j].y*qv[j].y + qv[j].z*qv[j].z + qv[j].w*qv[j].w;
            }
            #pragma unroll
            for (int off = 32; off >= 1; off >>= 1) ss += __shfl_xor(ss, off);
            const float qn = 0.5f / fmaxf(sqrtf(ss), 1e-12f);   // folds ALPHA=0.5

            float4 uv[4];
            float ss2 = 0.f;
            #pragma unroll
            for (int j = 0; j < 4; ++j) {
                float4 av = ((const float4*)s_anchor)[lane + 64 * j];
                uv[j].x = qv[j].x * qn + 0.5f * av.x;
                uv[j].y = qv[j].y * qn + 0.5f * av.y;
                uv[j].z = qv[j].z * qn + 0.5f * av.z;
                uv[j].w = qv[j].w * qn + 0.5f * av.w;
                ss2 += uv[j].x*uv[j].x + uv[j].y*uv[j].y + uv[j].z*uv[j].z + uv[j].w*uv[j].w;
            }
            #pragma unroll
            for (int off = 32; off >= 1; off >>= 1) ss2 += __shfl_xor(ss2, off);
            const float un = 1.0f / fmaxf(sqrtf(ss2), 1e-12f);
            #pragma unroll
            for (int j = 0; j < 4; ++j) {
                float4 w4 = make_float4(uv[j].x*un, uv[j].y*un, uv[j].z*un, uv[j].w*un);
                ((float4*)s_uq[t])[lane + 64 * j] = w4;
            }
            if (lane == 0) { s_tok[t] = tok; s_ttid[t] = tids[tok]; }
        }
        __syncthreads();

        // ---- scores: wave w owns slots [4w, 4w+4); runtime t-loop (anti-spill) ----
        {
            const float4* kr = (const float4*)(skeys + ((size_t)bucket * SLOTS + wid * 4) * D);
            float4 k0[4], k1[4], k2[4], k3[4];
            #pragma unroll
            for (int j = 0; j < 4; ++j) {
                k0[j] = kr[0 * D4 + lane + 64 * j];
                k1[j] = kr[1 * D4 + lane + 64 * j];
                k2[j] = kr[2 * D4 + lane + 64 * j];
                k3[j] = kr[3 * D4 + lane + 64 * j];
            }
            for (int t = 0; t < nt; ++t) {
                const float4* u4 = (const float4*)s_uq[t];
                float P0 = 0.f, P1 = 0.f, P2 = 0.f, P3 = 0.f;
                #pragma unroll
                for (int j = 0; j < 4; ++j) {
                    float4 u = u4[lane + 64 * j];
                    P0 += k0[j].x*u.x + k0[j].y*u.y + k0[j].z*u.z + k0[j].w*u.w;
                    P1 += k1[j].x*u.x + k1[j].y*u.y + k1[j].z*u.z + k1[j].w*u.w;
                    P2 += k2[j].x*u.x + k2[j].y*u.y + k2[j].z*u.z + k2[j].w*u.w;
                    P3 += k3[j].x*u.x + k3[j].y*u.y + k3[j].z*u.z + k3[j].w*u.w;
                }
                // batched paired-halving reduce: 4 values, 7 shfl total.
                // stage o=1: fold {P0,P2}->P0, {P1,P3}->P1 across lane-pairs
                {
                    const bool hi = (lane & 1) != 0;
                    const float sA = hi ? P0 : P2, kA = hi ? P2 : P0;
                    P0 = kA + __shfl_xor(sA, 1);
                    const float sB = hi ? P1 : P3, kB = hi ? P3 : P1;
                    P1 = kB + __shfl_xor(sB, 1);
                }
                // stage o=2: fold {P0,P1}->P0
                {
                    const bool hi = (lane & 2) != 0;
                    const float sA = hi ? P0 : P1, kA = hi ? P1 : P0;
                    P0 = kA + __shfl_xor(sA, 2);
                }
                P0 += __shfl_xor(P0, 4);
                P0 += __shfl_xor(P0, 8);
                P0 += __shfl_xor(P0, 16);
                P0 += __shfl_xor(P0, 32);
                // lane l<4 holds slot id = ((l&1)<<1)|((l>>1)&1)
                if (lane < 4)
                    s_scores[t][wid * 4 + (((lane & 1) << 1) | ((lane >> 1) & 1))] = P0;
            }
        }
        __syncthreads();

        // ---- softmax + hard-match: wave w owns tokens w, w+8; lanes 0..31 ----
        for (int t = wid; t < nt; t += 8) {
            if (lane < 32) {
                const int s = lane;
                const float sc = s_scores[t][s];
                const int match = (stids[bucket * SLOTS + s] == s_ttid[t]) ? 1 : 0;
                float mx = sc;
                #pragma unroll
                for (int off = 16; off >= 1; off >>= 1) mx = fmaxf(mx, __shfl_xor(mx, off));
                const float e = __expf((sc - mx) * TAU_INV);
                float es = e;
                int   ms = match;
                #pragma unroll
                for (int off = 16; off >= 1; off >>= 1) {
                    es += __shfl_xor(es, off);
                    ms += __shfl_xor(ms, off);
                }
                float p;
                if (ms > 0) p = (float)match / ((float)ms + 1e-9f);
                else        p = e / es;
                s_probs[t][s] = p;
            }
        }
        __syncthreads();

        // ---- values: grp = tidx>>8 (0/1) covers slots [16g,16g+16); col = tidx&255.
        //      Each grp: 2 rounds of 8 row-loads in flight, partial acc for all 16 tokens.
        {
            const int col = tidx & 255;
            const int grp = tidx >> 8;
            float4 acc[TC];
            #pragma unroll
            for (int t = 0; t < TC; ++t) acc[t] = make_float4(0.f, 0.f, 0.f, 0.f);

            const float4* vb = (const float4*)(svals + ((size_t)bucket * SLOTS + grp * 16) * D);
            #pragma unroll
            for (int s0 = 0; s0 < 16; s0 += 8) {
                float4 v[8];
                #pragma unroll
                for (int i = 0; i < 8; ++i) v[i] = vb[(s0 + i) * D4 + col];
                #pragma unroll
                for (int t = 0; t < TC; ++t) {
                    if (t < nt) {
                        const float4 pA = ((const float4*)s_probs[t])[grp*4 + (s0>>3)*2 + 0];
                        const float4 pB = ((const float4*)s_probs[t])[grp*4 + (s0>>3)*2 + 1];
                        acc[t].x += pA.x*v[0].x + pA.y*v[1].x + pA.z*v[2].x + pA.w*v[3].x
                                  + pB.x*v[4].x + pB.y*v[5].x + pB.z*v[6].x + pB.w*v[7].x;
                        acc[t].y += pA.x*v[0].y + pA.y*v[1].y + pA.z*v[2].y + pA.w*v[3].y
                                  + pB.x*v[4].y + pB.y*v[5].y + pB.z*v[6].y + pB.w*v[7].y;
                        acc[t].z += pA.x*v[0].z + pA.y*v[1].z + pA.z*v[2].z + pA.w*v[3].z
                                  + pB.x*v[4].z + pB.y*v[5].z + pB.z*v[6].z + pB.w*v[7].z;
                        acc[t].w += pA.x*v[0].w + pA.y*v[1].w + pA.z*v[2].w + pA.w*v[3].w
                                  + pB.x*v[4].w + pB.y*v[5].w + pB.z*v[6].w + pB.w*v[7].w;
                    }
                }
            }
            // combine the two slot-half partials through LDS (reuse s_uq)
            if (grp == 0) {
                #pragma unroll
                for (int t = 0; t < TC; ++t)
                    if (t < nt) ((float4*)s_uq[t])[col] = acc[t];
            }
            __syncthreads();
            if (grp == 1) {
                #pragma unroll
                for (int t = 0; t < TC; ++t) {
                    if (t < nt) {
                        float4 b = ((float4*)s_uq[t])[col];
                        float4 r = make_float4(acc[t].x + b.x, acc[t].y + b.y,
                                               acc[t].z + b.z, acc[t].w + b.w);
                        ((float4*)(out + (size_t)s_tok[t] * D))[col] = r;
                    }
                }
            }
        }
        __syncthreads();   // LDS reused next chunk
    }
}

extern "C" void kernel_launch(void* const* d_in, const int* in_sizes, int n_in,
                              void* d_out, int out_size, void* d_ws, size_t ws_size,
                              hipStream_t stream) {
    const float* query    = (const float*)d_in[0];
    const int*   tids     = (const int*)  d_in[1];
    const float* skeys    = (const float*)d_in[2];
    const float* svals    = (const float*)d_in[3];
    const int*   stids    = (const int*)  d_in[4];
    const float* centroid = (const float*)d_in[5];
    float* out = (float*)d_out;
    const int n_tokens = in_sizes[1];

    int* cnt  = (int*)d_ws;             // [NB]
    int* list = cnt + NB;               // [NB*CAP]

    k_zero<<<1, NB, 0, stream>>>(cnt);
    k_build<<<(n_tokens + 255) / 256, 256, 0, stream>>>(tids, n_tokens, cnt, list);
    k_main<<<NB, BT, 0, stream>>>(query, tids, skeys, svals, stids,
                                  centroid, out, cnt, list);
}

// Round 11
// 55.648 us; speedup vs baseline: 7.8604x; 1.1176x over previous
//
#include <hip/hip_runtime.h>

#define NB 512
#define SLOTS 32
#define D 1024
#define D4 256           // D/4 (float4 per row)
#define TC 8             // tokens per chunk (per part)
#define CAP 64           // list capacity per bucket
#define TAU_INV 10.0f
#define BT 256           // threads per block (4 waves)

// ---- kernel 0: zero the per-bucket counters ----
__global__ void k_zero(int* __restrict__ cnt) {
    if (threadIdx.x < NB) cnt[threadIdx.x] = 0;
}

// ---- kernel 1: build per-bucket token lists (order nondeterministic, but
//      per-token math is order-invariant → deterministic output) ----
__global__ void k_build(const int* __restrict__ tids, int n,
                        int* __restrict__ cnt, int* __restrict__ list) {
    int i = blockIdx.x * 256 + threadIdx.x;
    if (i < n) {
        int b = tids[i] & (NB - 1);
        int p = atomicAdd(&cnt[b], 1);
        if (p < CAP) list[b * CAP + p] = i;
    }
}

// ---- kernel 2: block = (bucket, parity), 4 waves, TC=8.
//      ~34 KB LDS + VGPR≤128 → 4 blocks/CU = 4 independent barrier groups
//      (R10 had 2 → 16.6% occupancy). Anti-spill: unroll-1 on round loops,
//      named scalars, runtime t-loop (R7-R9 post-mortems).
__global__ __launch_bounds__(BT, 2)
void k_main(const float* __restrict__ query,    // [NT][D]
            const int*   __restrict__ tids,     // [NT]
            const float* __restrict__ skeys,    // [NB*SLOTS][D]
            const float* __restrict__ svals,    // [NB*SLOTS][D]
            const int*   __restrict__ stids,    // [NB*SLOTS]
            const float* __restrict__ centroid, // [NB][D]
            float*       __restrict__ out,      // [NT][D]
            const int*   __restrict__ cnt,
            const int*   __restrict__ list)
{
    const int bucket = blockIdx.x & (NB - 1);   // parts share XCD (512%8==0)
    const int part   = blockIdx.x >> 9;         // 0/1
    const int tidx   = threadIdx.x;             // 0..255
    const int lane   = tidx & 63;
    const int wid    = tidx >> 6;               // 0..3

    const int count = min(cnt[bucket], CAP);
    const int ncnt  = (count - part + 1) >> 1;  // tokens owned by this part
    if (ncnt <= 0) return;

    __shared__ float s_uq[TC][D];               // 32 KB
    __shared__ float s_scores[TC][SLOTS];       // 1 KB
    __shared__ float s_probs[TC][SLOTS];        // 1 KB
    __shared__ int   s_tok[TC];
    __shared__ int   s_ttid[TC];

    const int slot_tid = stids[bucket * SLOTS + (lane & 31)];
    const float4* kb = (const float4*)(skeys + (size_t)bucket * SLOTS * D);
    const float4* vb = (const float4*)(svals + (size_t)bucket * SLOTS * D);
    const float4* cb = (const float4*)(centroid + (size_t)bucket * D);

    for (int c0 = 0; c0 < ncnt; c0 += TC) {
        const int nt = min(TC, ncnt - c0);

        // ---- query phase: wave w owns tokens w, w+4 (anchor from L2) ----
        for (int t = wid; t < nt; t += 4) {
            const int tok = list[bucket * CAP + part + 2 * (c0 + t)];
            const float4* q4 = (const float4*)(query + (size_t)tok * D);
            float4 qv[4], anc[4];
            float ss = 0.f;
            #pragma unroll
            for (int j = 0; j < 4; ++j) {
                qv[j]  = q4[lane + 64 * j];
                anc[j] = cb[lane + 64 * j];
                ss += qv[j].x*qv[j].x + qv[j].y*qv[j].y + qv[j].z*qv[j].z + qv[j].w*qv[j].w;
            }
            #pragma unroll
            for (int off = 32; off >= 1; off >>= 1) ss += __shfl_xor(ss, off);
            const float qn = 0.5f / fmaxf(sqrtf(ss), 1e-12f);   // folds ALPHA=0.5
            float4 uv[4];
            float ss2 = 0.f;
            #pragma unroll
            for (int j = 0; j < 4; ++j) {
                uv[j].x = qv[j].x * qn + 0.5f * anc[j].x;
                uv[j].y = qv[j].y * qn + 0.5f * anc[j].y;
                uv[j].z = qv[j].z * qn + 0.5f * anc[j].z;
                uv[j].w = qv[j].w * qn + 0.5f * anc[j].w;
                ss2 += uv[j].x*uv[j].x + uv[j].y*uv[j].y + uv[j].z*uv[j].z + uv[j].w*uv[j].w;
            }
            #pragma unroll
            for (int off = 32; off >= 1; off >>= 1) ss2 += __shfl_xor(ss2, off);
            const float un = 1.0f / fmaxf(sqrtf(ss2), 1e-12f);
            #pragma unroll
            for (int j = 0; j < 4; ++j) {
                ((float4*)s_uq[t])[lane + 64 * j] =
                    make_float4(uv[j].x*un, uv[j].y*un, uv[j].z*un, uv[j].w*un);
            }
            if (lane == 0) { s_tok[t] = tok; s_ttid[t] = tids[tok]; }
        }
        __syncthreads();

        // ---- scores: 2 sequential rounds; wave owns 4 slots/round ----
        #pragma unroll 1
        for (int rnd = 0; rnd < 2; ++rnd) {
            const int sbase = rnd * 16 + wid * 4;
            const float4* kr = kb + (size_t)sbase * D4;
            float4 k0[4], k1[4], k2[4], k3[4];
            #pragma unroll
            for (int j = 0; j < 4; ++j) {
                k0[j] = kr[0 * D4 + lane + 64 * j];
                k1[j] = kr[1 * D4 + lane + 64 * j];
                k2[j] = kr[2 * D4 + lane + 64 * j];
                k3[j] = kr[3 * D4 + lane + 64 * j];
            }
            for (int t = 0; t < nt; ++t) {          // runtime bound: anti-spill
                const float4* u4 = (const float4*)s_uq[t];
                float P0 = 0.f, P1 = 0.f, P2 = 0.f, P3 = 0.f;
                #pragma unroll
                for (int j = 0; j < 4; ++j) {
                    float4 u = u4[lane + 64 * j];
                    P0 += k0[j].x*u.x + k0[j].y*u.y + k0[j].z*u.z + k0[j].w*u.w;
                    P1 += k1[j].x*u.x + k1[j].y*u.y + k1[j].z*u.z + k1[j].w*u.w;
                    P2 += k2[j].x*u.x + k2[j].y*u.y + k2[j].z*u.z + k2[j].w*u.w;
                    P3 += k3[j].x*u.x + k3[j].y*u.y + k3[j].z*u.z + k3[j].w*u.w;
                }
                // batched paired-halving reduce: 4 values, 7 shfl (R10-verified)
                {
                    const bool hi = (lane & 1) != 0;
                    const float sA = hi ? P0 : P2, kA = hi ? P2 : P0;
                    P0 = kA + __shfl_xor(sA, 1);
                    const float sB = hi ? P1 : P3, kB = hi ? P3 : P1;
                    P1 = kB + __shfl_xor(sB, 1);
                }
                {
                    const bool hi = (lane & 2) != 0;
                    const float sA = hi ? P0 : P1, kA = hi ? P1 : P0;
                    P0 = kA + __shfl_xor(sA, 2);
                }
                P0 += __shfl_xor(P0, 4);
                P0 += __shfl_xor(P0, 8);
                P0 += __shfl_xor(P0, 16);
                P0 += __shfl_xor(P0, 32);
                // lane l<4 holds slot id = ((l&1)<<1)|((l>>1)&1)
                if (lane < 4)
                    s_scores[t][sbase + (((lane & 1) << 1) | ((lane >> 1) & 1))] = P0;
            }
        }
        __syncthreads();

        // ---- softmax + hard-match: wave w owns tokens w, w+4; lanes 0..31 ----
        for (int t = wid; t < nt; t += 4) {
            if (lane < 32) {
                const float sc = s_scores[t][lane];
                float mx = sc;
                #pragma unroll
                for (int off = 16; off >= 1; off >>= 1) mx = fmaxf(mx, __shfl_xor(mx, off));
                const float e = __expf((sc - mx) * TAU_INV);
                const float f = (slot_tid == s_ttid[t]) ? 1.f : 0.f;
                float es = e, ms = f;
                #pragma unroll
                for (int off = 16; off >= 1; off >>= 1) {
                    es += __shfl_xor(es, off);
                    ms += __shfl_xor(ms, off);
                }
                s_probs[t][lane] = (ms > 0.f) ? f / (ms + 1e-9f) : e / es;
            }
        }
        __syncthreads();

        // ---- values: thread owns float4 column tidx; 4 rounds of 8 rows ----
        {
            float4 acc[TC];
            #pragma unroll
            for (int t = 0; t < TC; ++t) acc[t] = make_float4(0.f, 0.f, 0.f, 0.f);

            #pragma unroll 1
            for (int s0 = 0; s0 < SLOTS; s0 += 8) {
                float4 v[8];
                #pragma unroll
                for (int i = 0; i < 8; ++i) v[i] = vb[(s0 + i) * D4 + tidx];
                #pragma unroll
                for (int t = 0; t < TC; ++t) {
                    if (t < nt) {
                        const float4 pA = ((const float4*)s_probs[t])[(s0 >> 2) + 0];
                        const float4 pB = ((const float4*)s_probs[t])[(s0 >> 2) + 1];
                        acc[t].x += pA.x*v[0].x + pA.y*v[1].x + pA.z*v[2].x + pA.w*v[3].x
                                  + pB.x*v[4].x + pB.y*v[5].x + pB.z*v[6].x + pB.w*v[7].x;
                        acc[t].y += pA.x*v[0].y + pA.y*v[1].y + pA.z*v[2].y + pA.w*v[3].y
                                  + pB.x*v[4].y + pB.y*v[5].y + pB.z*v[6].y + pB.w*v[7].y;
                        acc[t].z += pA.x*v[0].z + pA.y*v[1].z + pA.z*v[2].z + pA.w*v[3].z
                                  + pB.x*v[4].z + pB.y*v[5].z + pB.z*v[6].z + pB.w*v[7].z;
                        acc[t].w += pA.x*v[0].w + pA.y*v[1].w + pA.z*v[2].w + pA.w*v[3].w
                                  + pB.x*v[4].w + pB.y*v[5].w + pB.z*v[6].w + pB.w*v[7].w;
                    }
                }
            }
            #pragma unroll
            for (int t = 0; t < TC; ++t) {
                if (t < nt) {
                    ((float4*)(out + (size_t)s_tok[t] * D))[tidx] = acc[t];
                }
            }
        }
        __syncthreads();   // next chunk rewrites s_uq/s_tok
    }
}

extern "C" void kernel_launch(void* const* d_in, const int* in_sizes, int n_in,
                              void* d_out, int out_size, void* d_ws, size_t ws_size,
                              hipStream_t stream) {
    const float* query    = (const float*)d_in[0];
    const int*   tids     = (const int*)  d_in[1];
    const float* skeys    = (const float*)d_in[2];
    const float* svals    = (const float*)d_in[3];
    const int*   stids    = (const int*)  d_in[4];
    const float* centroid = (const float*)d_in[5];
    float* out = (float*)d_out;
    const int n_tokens = in_sizes[1];

    int* cnt  = (int*)d_ws;             // [NB]
    int* list = cnt + NB;               // [NB*CAP]

    k_zero<<<1, 512, 0, stream>>>(cnt);
    k_build<<<(n_tokens + 255) / 256, 256, 0, stream>>>(tids, n_tokens, cnt, list);
    k_main<<<NB * 2, BT, 0, stream>>>(query, tids, skeys, svals, stids,
                                      centroid, out, cnt, list);
}